// Round 5
// baseline (1287.108 us; speedup 1.0000x reference)
//
#include <hip/hip_runtime.h>

#define T 1024
#define BATCH 512
#define EMB 64
#define HID 64
#define NGATE 256        // 4*HID
#define VOCABP1 50001

__device__ __forceinline__ float fast_sigmoid(float x) {
    return 1.0f / (1.0f + __expf(-x));
}
__device__ __forceinline__ float fast_tanh(float x) {
    return 1.0f - 2.0f / (__expf(2.0f * x) + 1.0f);
}
__device__ __forceinline__ float bcastf(float v, int k) {
    return __int_as_float(__builtin_amdgcn_readlane(__float_as_int(v), k));
}
__device__ __forceinline__ int bcasti(int v, int k) {
    return __builtin_amdgcn_readlane(v, k);
}

// ---------------------------------------------------------------------------
// Kernel A: gate-interleaved zx table.
//   ztab[v][l][g] = bias[g*64+l] + sum_k emb[v][k] * W[k][g*64+l]
// LSTM thread (unit l, wave w) reads gates {2w,2w+1} as one float2.
// ---------------------------------------------------------------------------
__global__ __launch_bounds__(256, 3)
void zxtab_kernel(const float* __restrict__ emb,
                  const float* __restrict__ Wf, const float* __restrict__ bf,
                  const float* __restrict__ Wb, const float* __restrict__ bb,
                  float* __restrict__ zf_tab, float* __restrict__ zb_tab)
{
    const int j    = threadIdx.x;       // output slot: l = j>>2, g = j&3
    const int lane = j & 63;
    const int col  = (j & 3) * 64 + (j >> 2);   // original gate column
    float wf[EMB], wb[EMB];
#pragma unroll
    for (int k = 0; k < EMB; ++k) wf[k] = Wf[k * NGATE + col];
#pragma unroll
    for (int k = 0; k < EMB; ++k) wb[k] = Wb[k * NGATE + col];
    const float bfj = bf[col];
    const float bbj = bb[col];

    for (int r = blockIdx.x; r < VOCABP1; r += gridDim.x) {
        const float ev = emb[r * EMB + lane];   // lane k holds emb[r][k]
        float f0 = bfj, f1 = 0.f, b0 = bbj, b1 = 0.f;
#pragma unroll
        for (int k = 0; k < EMB; k += 2) {
            const float e0 = bcastf(ev, k);
            const float e1 = bcastf(ev, k + 1);
            f0 = fmaf(e0, wf[k],     f0);
            f1 = fmaf(e1, wf[k + 1], f1);
            b0 = fmaf(e0, wb[k],     b0);
            b1 = fmaf(e1, wb[k + 1], b1);
        }
        zf_tab[r * NGATE + j] = f0 + f1;
        zb_tab[r * NGATE + j] = b0 + b1;
    }
}

// ---------------------------------------------------------------------------
// Kernel B: recurrence. One block = one (batch, dir), 128 threads (2 waves).
// lane l = hidden unit; wave 0 owns gates {i,f}, wave 1 owns {g,o}.
// R4 failure: compiler demoted u0[]/u1[] to AGPRs -> v_accvgpr_read per FMA
// (555 inst/step measured vs 250 intended, VGPR_Count=88). Fix: every weight
// use is an inline-asm v_fmac with a "v" register-class constraint, forcing
// arch-VGPR residency. h broadcast stays v_readlane -> "s" operand (src0).
// ---------------------------------------------------------------------------
#define MAC2(k)                                                               \
  {                                                                           \
    const float h0 = bcastf(hval, (k));                                       \
    const float h1 = bcastf(hval, (k) + 1);                                   \
    asm("v_fmac_f32 %0, %1, %2" : "+v"(z0) : "s"(h0), "v"(u0[(k)]));          \
    asm("v_fmac_f32 %0, %1, %2" : "+v"(z1) : "s"(h0), "v"(u1[(k)]));          \
    asm("v_fmac_f32 %0, %1, %2" : "+v"(z2) : "s"(h1), "v"(u0[(k) + 1]));      \
    asm("v_fmac_f32 %0, %1, %2" : "+v"(z3) : "s"(h1), "v"(u1[(k) + 1]));      \
  }
#define MAC8(k) MAC2(k) MAC2((k)+2) MAC2((k)+4) MAC2((k)+6)

__global__
__attribute__((amdgpu_flat_work_group_size(128, 128), amdgpu_waves_per_eu(2, 2)))
void lstm_kernel(const int* __restrict__ x,
                 const float* __restrict__ Uf, const float* __restrict__ Ub,
                 const float* __restrict__ zf_tab,
                 const float* __restrict__ zb_tab,
                 float* __restrict__ hcat)    // [BATCH][2*HID]
{
    const int tid = threadIdx.x;
    const int l   = tid & 63;          // lane = hidden unit
    const int w   = tid >> 6;          // 0: {i,f}, 1: {g,o}
    const int b   = blockIdx.x >> 1;
    const int d   = blockIdx.x & 1;

    const float* U    = d ? Ub : Uf;
    const float* ztab = d ? zb_tab : zf_tab;

    // owned columns: c0 = (2w)*64 + l, c1 = (2w+1)*64 + l
    float u0[HID], u1[HID];
#pragma unroll
    for (int k = 0; k < HID; ++k) u0[k] = U[k * NGATE + (2 * w) * 64 + l];
#pragma unroll
    for (int k = 0; k < HID; ++k) u1[k] = U[k * NGATE + (2 * w + 1) * 64 + l];

    __shared__ float zs[2][2][2][64];   // [buf][wave][which][unit]

    float hval = 0.0f;                  // lane l: h[l] (replicated per wave)
    float cval = 0.0f;

    const int* xrow = x + b * T;

    // token chunks: lane s holds token for step base+s
    auto tok_idx = [&](int s) -> int {
        s = s < (T - 1) ? s : (T - 1);
        return d ? (T - 1 - s) : s;
    };
    int tok_chunk      = xrow[tok_idx(l)];
    int tok_next_chunk = xrow[tok_idx(64 + l)];

    int tok = bcasti(tok_chunk, 0);
    const float2* zt2 = (const float2*)ztab;
    float2 zcur = zt2[(size_t)tok * 128 + l * 2 + w];

    for (int s = 0; s < T; ++s) {
        // ---- prefetch step s+1 ----
        const int tnl = (s + 1) & 63;
        if (tnl == 0) {                       // entering a new chunk at s+1
            tok_chunk = tok_next_chunk;
            tok_next_chunk = xrow[tok_idx(s + 65 + l)];
        }
        const int tok1 = bcasti(tok_chunk, tnl);
        const float2 znext = zt2[(size_t)tok1 * 128 + l * 2 + w];

        // ---- z = zx + h . U (forced-VGPR asm FMAs) ----
        float z0 = zcur.x, z1 = zcur.y, z2 = 0.f, z3 = 0.f;
        MAC8(0)  MAC8(8)  MAC8(16) MAC8(24)
        MAC8(32) MAC8(40) MAC8(48) MAC8(56)
        const float za = z0 + z2;   // gate 2w   (i or g)
        const float zb = z1 + z3;   // gate 2w+1 (f or o)

        // wave-uniform activation: wave1's first gate is g -> tanh
        const float a0 = w ? fast_tanh(za) : fast_sigmoid(za);
        const float a1 = fast_sigmoid(zb);

        float (*buf)[2][64] = zs[s & 1];
        buf[w][0][l] = a0;
        buf[w][1][l] = a1;
        __syncthreads();                      // the only barrier per step

        const float b0 = buf[1 - w][0][l];
        const float b1 = buf[1 - w][1][l];

        // wave0: a=(i,f) b=(g,o);  wave1: a=(g,o) b=(i,f)
        const float ig = w ? b0 : a0;
        const float fg = w ? b1 : a1;
        const float gg = w ? a0 : b0;
        const float og = w ? a1 : b1;

        const float cn = fmaf(fg, cval, ig * gg);
        const float hn = og * fast_tanh(cn);
        if (tok != 0) { cval = cn; hval = hn; }   // pad mask (uniform)

        tok  = tok1;
        zcur = znext;
        // double-buffered zs: rewrite of buf[s&1] happens only after barrier
        // s+1, which every wave reaches only after its reads above.
    }

    if (w == 0) hcat[b * (2 * HID) + d * HID + l] = hval;
}

// ---------------------------------------------------------------------------
// Tiny MLP head: out[b] = relu(hcat[b] @ W1 + b1) @ W2 + b2
// ---------------------------------------------------------------------------
__global__ void mlp_kernel(const float* __restrict__ hcat,
                           const float* __restrict__ W1, const float* __restrict__ b1,
                           const float* __restrict__ W2, const float* __restrict__ b2,
                           float* __restrict__ out)
{
    const int b = blockIdx.x;
    const int tid = threadIdx.x;  // 64 threads
    __shared__ float h1[32];
    const float* h = hcat + b * (2 * HID);
    if (tid < 32) {
        float acc = b1[tid];
#pragma unroll
        for (int k = 0; k < 2 * HID; ++k) acc += h[k] * W1[k * 32 + tid];
        h1[tid] = fmaxf(acc, 0.0f);
    }
    __syncthreads();
    if (tid == 0) {
        float acc = b2[0];
#pragma unroll
        for (int m = 0; m < 32; ++m) acc += h1[m] * W2[m];
        out[b] = acc;
    }
}

extern "C" void kernel_launch(void* const* d_in, const int* in_sizes, int n_in,
                              void* d_out, int out_size, void* d_ws, size_t ws_size,
                              hipStream_t stream)
{
    const int*   x   = (const int*)d_in[0];
    const float* emb = (const float*)d_in[1];
    const float* Wf  = (const float*)d_in[2];
    const float* Uf  = (const float*)d_in[3];
    const float* bf  = (const float*)d_in[4];
    const float* Wb  = (const float*)d_in[5];
    const float* Ub  = (const float*)d_in[6];
    const float* bb  = (const float*)d_in[7];
    const float* W1  = (const float*)d_in[8];
    const float* b1  = (const float*)d_in[9];
    const float* W2  = (const float*)d_in[10];
    const float* b2  = (const float*)d_in[11];
    float* out = (float*)d_out;

    // workspace layout: [zf_tab | zb_tab | hcat]
    float* zf_tab = (float*)d_ws;                               // 50001*256 f32
    float* zb_tab = zf_tab + (size_t)VOCABP1 * NGATE;           // 50001*256 f32
    float* hcat   = zb_tab + (size_t)VOCABP1 * NGATE;           // 512*128  f32

    zxtab_kernel<<<dim3(2048), dim3(256), 0, stream>>>(
        emb, Wf, bf, Wb, bb, zf_tab, zb_tab);
    lstm_kernel<<<dim3(2 * BATCH), dim3(128), 0, stream>>>(
        x, Uf, Ub, zf_tab, zb_tab, hcat);
    mlp_kernel<<<dim3(BATCH), dim3(64), 0, stream>>>(
        hcat, W1, b1, W2, b2, out);
}

// Round 6
// 1243.686 us; speedup vs baseline: 1.0349x; 1.0349x over previous
//
#include <hip/hip_runtime.h>

#define T 1024
#define BATCH 512
#define EMB 64
#define HID 64
#define NGATE 256
#define VOCABP1 50001

typedef unsigned int uint32;
typedef unsigned short ushort16;
typedef __attribute__((ext_vector_type(8))) short short8;   // 8 bf16 = 4 VGPRs
typedef __attribute__((ext_vector_type(4))) float f32x4;    // MFMA C/D

__device__ __forceinline__ float rcpf(float x) { return __builtin_amdgcn_rcpf(x); }
__device__ __forceinline__ float sigm(float x) { return rcpf(1.0f + __expf(-x)); }
__device__ __forceinline__ float tanhfast(float x) { return 1.0f - 2.0f * rcpf(__expf(2.0f * x) + 1.0f); }
__device__ __forceinline__ float bcastf(float v, int k) {
    return __int_as_float(__builtin_amdgcn_readlane(__float_as_int(v), k));
}
__device__ __forceinline__ ushort16 f2bf(float x) {        // RNE f32->bf16 (no NaN inputs)
    uint32 u = __float_as_uint(x);
    u += 0x7fffu + ((u >> 16) & 1u);
    return (ushort16)(u >> 16);
}
__device__ __forceinline__ float bf2f(ushort16 h) { return __uint_as_float(((uint32)h) << 16); }

// ---------------------------------------------------------------------------
// zx table, natural layout: ztab[v][col] = b[col] + sum_k emb[v][k]*W[k][col]
// ---------------------------------------------------------------------------
__global__ __launch_bounds__(256, 3)
void zxtab_kernel(const float* __restrict__ emb,
                  const float* __restrict__ Wf, const float* __restrict__ bf,
                  const float* __restrict__ Wb, const float* __restrict__ bb,
                  float* __restrict__ zf_tab, float* __restrict__ zb_tab)
{
    const int j = threadIdx.x;
    const int lane = j & 63;
    float wf[EMB], wb[EMB];
#pragma unroll
    for (int k = 0; k < EMB; ++k) wf[k] = Wf[k * NGATE + j];
#pragma unroll
    for (int k = 0; k < EMB; ++k) wb[k] = Wb[k * NGATE + j];
    const float bfj = bf[j];
    const float bbj = bb[j];
    for (int r = blockIdx.x; r < VOCABP1; r += gridDim.x) {
        const float ev = emb[r * EMB + lane];
        float f0 = bfj, f1 = 0.f, b0 = bbj, b1 = 0.f;
#pragma unroll
        for (int k = 0; k < EMB; k += 2) {
            const float e0 = bcastf(ev, k);
            const float e1 = bcastf(ev, k + 1);
            f0 = fmaf(e0, wf[k], f0);
            f1 = fmaf(e1, wf[k + 1], f1);
            b0 = fmaf(e0, wb[k], b0);
            b1 = fmaf(e1, wb[k + 1], b1);
        }
        zf_tab[r * NGATE + j] = f0 + f1;
        zb_tab[r * NGATE + j] = b0 + b1;
    }
}

// ---------------------------------------------------------------------------
// Step-ordered token streams: xs[d][b][s] = x[b][ d ? T-1-s : s ]
// ---------------------------------------------------------------------------
__global__ void xsprep_kernel(const int* __restrict__ x, int* __restrict__ xs)
{
    const int idx = blockIdx.x * 256 + threadIdx.x;       // 2*512*1024 total
    const int d = idx >> 19;
    const int b = (idx >> 10) & 511;
    const int s = idx & 1023;
    xs[idx] = x[b * T + (d ? (T - 1 - s) : s)];
}

// ---------------------------------------------------------------------------
// B-fragment prep: U (hi/lo bf16 split) laid out in MFMA B-frag order.
//   idx(d,w,g,ks,var,lane,j) = ((((((d*4+w)*4+g)*2+ks)*2+var)*64)+lane)*8+j
//   value = split(U[k][col]),  k = ks*32+(lane>>4)*8+j,  col = g*64+16w+(lane&15)
// B-frag lane map (symmetric to verified A map): n=lane&15, k=(lane>>4)*8+j.
// ---------------------------------------------------------------------------
__global__ void bfrag_kernel(const float* __restrict__ Uf,
                             const float* __restrict__ Ub,
                             ushort16* __restrict__ bfrag)
{
    const int d = blockIdx.x;                 // 0 fwd, 1 bwd
    const float* U = d ? Ub : Uf;
    const int tid = threadIdx.x, lane = tid & 63, w = tid >> 6;
#pragma unroll
    for (int g = 0; g < 4; ++g)
#pragma unroll
    for (int ks = 0; ks < 2; ++ks)
#pragma unroll
    for (int j = 0; j < 8; ++j) {
        const int col = g * 64 + 16 * w + (lane & 15);
        const int k   = ks * 32 + (lane >> 4) * 8 + j;
        const float uv = U[k * NGATE + col];
        const ushort16 hi = f2bf(uv);
        const ushort16 lo = f2bf(uv - bf2f(hi));
        const size_t base = ((((size_t)(d * 4 + w) * 4 + g) * 2 + ks) * 2) * 512;
        bfrag[base + 0 * 512 + lane * 8 + j] = hi;
        bfrag[base + 1 * 512 + lane * 8 + j] = lo;
    }
}

// ---------------------------------------------------------------------------
// MFMA LSTM: 64 blocks (32 fwd + 32 bwd) x 256 threads; 16 sequences/block.
// Wave w owns units [16w,16w+16) for all 4 gates (tiles g=0..3).
// Per step: acc[g] = zx (C-init, f32 exact) + hi/lo-split bf16 MFMA of h@U.
// h round-trips LDS: C-layout (row=quad*4+reg=batch, col=lane&15=unit-in-16)
// -> A-layout (m=lane&15=batch, k=(lane>>4)*8+j=unit). AGPR demotion of the
// 64-reg B-frags is harmless: MFMA reads AGPRs natively (the R2-R5 VALU
// designs died on v_accvgpr_read copies; VALU has no AGPR src on gfx950).
// ---------------------------------------------------------------------------
__global__ __launch_bounds__(256, 1)
void lstm_mfma(const int* __restrict__ xs,
               const float* __restrict__ zf_tab,
               const float* __restrict__ zb_tab,
               const ushort16* __restrict__ bfrag,
               float* __restrict__ hcat)
{
    const int tid  = threadIdx.x;
    const int lane = tid & 63;
    const int w    = tid >> 6;          // unit group
    const int col  = lane & 15;
    const int quad = lane >> 4;
    const int d    = blockIdx.x >> 5;
    const int gb   = blockIdx.x & 31;   // batch group: batches 16gb..16gb+15

    const float* ztab = d ? zb_tab : zf_tab;
    const int ucol = 16 * w + col;              // global unit of this thread
    const int KS   = w >> 1;                    // unit>>5, wave-uniform
    const int q2   = (2 * w + (col >> 3)) & 3;  // (unit>>3)&3

    // B fragments (hi/lo): 16 x short8 — AGPR-friendly
    short8 Bf[4][2][2];
    {
        const ushort16* p = bfrag + ((size_t)(d * 4 + w) * 4) * 2 * 2 * 512;
#pragma unroll
        for (int g = 0; g < 4; ++g)
#pragma unroll
        for (int ks = 0; ks < 2; ++ks)
#pragma unroll
        for (int v = 0; v < 2; ++v)
            Bf[g][ks][v] = *(const short8*)&p[(((g * 2 + ks) * 2 + v) * 64 + lane) * 8];
    }

    __shared__ ushort16 A_lds[2][2][2][64][8];  // [buf][var][ks][q'*16+m][j]
    __shared__ int tokbuf[2][16];

    // zero h_{-1} fragments (both buffers)
    {
        ushort16* f = &A_lds[0][0][0][0][0];
        for (int i = tid; i < 2 * 2 * 2 * 64 * 8; i += 256) f[i] = 0;
    }
    const int* xrow_w = xs + ((size_t)(d * 512 + gb * 16 + (tid & 15))) * T;
    if (tid < 16) {
        tokbuf[0][tid] = xrow_w[0];
        tokbuf[1][tid] = xrow_w[1];
    }
    __syncthreads();

    int   tokc[4];
#pragma unroll
    for (int r = 0; r < 4; ++r) tokc[r] = tokbuf[0][quad * 4 + r];
    float zxC[4][4];
#pragma unroll
    for (int g = 0; g < 4; ++g)
#pragma unroll
    for (int r = 0; r < 4; ++r)
        zxC[g][r] = ztab[(size_t)tokc[r] * NGATE + g * 64 + ucol];

    float hv[4] = {0.f, 0.f, 0.f, 0.f};
    float cv[4] = {0.f, 0.f, 0.f, 0.f};

#define STEP(SV, P)                                                            \
  {                                                                            \
    __syncthreads();                                                           \
    short8 Ah0 = *(const short8*)&A_lds[1 - (P)][0][0][lane][0];               \
    short8 Ah1 = *(const short8*)&A_lds[1 - (P)][0][1][lane][0];               \
    short8 Al0 = *(const short8*)&A_lds[1 - (P)][1][0][lane][0];               \
    short8 Al1 = *(const short8*)&A_lds[1 - (P)][1][1][lane][0];               \
    int tn[4];                                                                 \
    _Pragma("unroll")                                                          \
    for (int r = 0; r < 4; ++r) tn[r] = tokbuf[1 - (P)][quad * 4 + r];         \
    float zxN[4][4];                                                           \
    _Pragma("unroll")                                                          \
    for (int g = 0; g < 4; ++g)                                                \
      _Pragma("unroll")                                                        \
      for (int r = 0; r < 4; ++r)                                              \
        zxN[g][r] = ztab[(size_t)tn[r] * NGATE + g * 64 + ucol];               \
    if (tid < 16) tokbuf[(P)][tid] = ((SV) + 2 < T) ? xrow_w[(SV) + 2] : 0;    \
    f32x4 acc[4];                                                              \
    _Pragma("unroll")                                                          \
    for (int g = 0; g < 4; ++g) {                                              \
      acc[g][0] = zxC[g][0]; acc[g][1] = zxC[g][1];                            \
      acc[g][2] = zxC[g][2]; acc[g][3] = zxC[g][3];                            \
    }                                                                          \
    _Pragma("unroll")                                                          \
    for (int g = 0; g < 4; ++g) {                                              \
      acc[g] = __builtin_amdgcn_mfma_f32_16x16x32_bf16(Ah0, Bf[g][0][0], acc[g], 0, 0, 0); \
      acc[g] = __builtin_amdgcn_mfma_f32_16x16x32_bf16(Ah1, Bf[g][1][0], acc[g], 0, 0, 0); \
      acc[g] = __builtin_amdgcn_mfma_f32_16x16x32_bf16(Ah0, Bf[g][0][1], acc[g], 0, 0, 0); \
      acc[g] = __builtin_amdgcn_mfma_f32_16x16x32_bf16(Ah1, Bf[g][1][1], acc[g], 0, 0, 0); \
      acc[g] = __builtin_amdgcn_mfma_f32_16x16x32_bf16(Al0, Bf[g][0][0], acc[g], 0, 0, 0); \
      acc[g] = __builtin_amdgcn_mfma_f32_16x16x32_bf16(Al1, Bf[g][1][0], acc[g], 0, 0, 0); \
    }                                                                          \
    _Pragma("unroll")                                                          \
    for (int r = 0; r < 4; ++r) {                                              \
      const float iv = sigm(acc[0][r]);                                        \
      const float fv = sigm(acc[1][r]);                                        \
      const float gv = tanhfast(acc[2][r]);                                    \
      const float ov = sigm(acc[3][r]);                                        \
      const float cn = fmaf(fv, cv[r], iv * gv);                               \
      const float hn = ov * tanhfast(cn);                                      \
      if (tokc[r] != 0) { cv[r] = cn; hv[r] = hn; }                            \
      const ushort16 hhi = f2bf(hv[r]);                                        \
      const ushort16 hlo = f2bf(hv[r] - bf2f(hhi));                            \
      A_lds[(P)][0][KS][q2 * 16 + quad * 4 + r][col & 7] = hhi;                \
      A_lds[(P)][1][KS][q2 * 16 + quad * 4 + r][col & 7] = hlo;                \
    }                                                                          \
    _Pragma("unroll")                                                          \
    for (int r = 0; r < 4; ++r) tokc[r] = tn[r];                               \
    _Pragma("unroll")                                                          \
    for (int g = 0; g < 4; ++g)                                                \
      _Pragma("unroll")                                                        \
      for (int r = 0; r < 4; ++r) zxC[g][r] = zxN[g][r];                       \
  }

    for (int s = 0; s < T; s += 2) {
        STEP(s, 0)
        STEP(s + 1, 1)
    }
#undef STEP

#pragma unroll
    for (int r = 0; r < 4; ++r)
        hcat[(size_t)(gb * 16 + quad * 4 + r) * (2 * HID) + d * HID + ucol] = hv[r];
}

// ---------------------------------------------------------------------------
// Tiny MLP head: out[b] = relu(hcat[b] @ W1 + b1) @ W2 + b2
// ---------------------------------------------------------------------------
__global__ void mlp_kernel(const float* __restrict__ hcat,
                           const float* __restrict__ W1, const float* __restrict__ b1,
                           const float* __restrict__ W2, const float* __restrict__ b2,
                           float* __restrict__ out)
{
    const int b = blockIdx.x;
    const int tid = threadIdx.x;  // 64 threads
    __shared__ float h1[32];
    const float* h = hcat + b * (2 * HID);
    if (tid < 32) {
        float acc = b1[tid];
#pragma unroll
        for (int k = 0; k < 2 * HID; ++k) acc += h[k] * W1[k * 32 + tid];
        h1[tid] = fmaxf(acc, 0.0f);
    }
    __syncthreads();
    if (tid == 0) {
        float acc = b2[0];
#pragma unroll
        for (int m = 0; m < 32; ++m) acc += h1[m] * W2[m];
        out[b] = acc;
    }
}

extern "C" void kernel_launch(void* const* d_in, const int* in_sizes, int n_in,
                              void* d_out, int out_size, void* d_ws, size_t ws_size,
                              hipStream_t stream)
{
    const int*   x   = (const int*)d_in[0];
    const float* emb = (const float*)d_in[1];
    const float* Wf  = (const float*)d_in[2];
    const float* Uf  = (const float*)d_in[3];
    const float* bf  = (const float*)d_in[4];
    const float* Wb  = (const float*)d_in[5];
    const float* Ub  = (const float*)d_in[6];
    const float* bb  = (const float*)d_in[7];
    const float* W1  = (const float*)d_in[8];
    const float* b1  = (const float*)d_in[9];
    const float* W2  = (const float*)d_in[10];
    const float* b2  = (const float*)d_in[11];
    float* out = (float*)d_out;

    // workspace: [zf_tab | zb_tab | xs | bfrag | hcat]
    float*    zf_tab = (float*)d_ws;                              // 12800256 f32
    float*    zb_tab = zf_tab + (size_t)VOCABP1 * NGATE;          // 12800256 f32
    int*      xs     = (int*)(zb_tab + (size_t)VOCABP1 * NGATE);  // 2*512*1024 i32
    ushort16* bfrag  = (ushort16*)(xs + 2 * 512 * 1024);          // 65536 u16
    float*    hcat   = (float*)(bfrag + 65536);                   // 512*128 f32

    zxtab_kernel<<<dim3(2048), dim3(256), 0, stream>>>(
        emb, Wf, bf, Wb, bb, zf_tab, zb_tab);
    xsprep_kernel<<<dim3(2 * 512 * 1024 / 256), dim3(256), 0, stream>>>(x, xs);
    bfrag_kernel<<<dim3(2), dim3(256), 0, stream>>>(Uf, Ub, bfrag);
    lstm_mfma<<<dim3(64), dim3(256), 0, stream>>>(xs, zf_tab, zb_tab, bfrag, hcat);
    mlp_kernel<<<dim3(BATCH), dim3(64), 0, stream>>>(hcat, W1, b1, W2, b2, out);
}